// Round 4
// baseline (219.787 us; speedup 1.0000x reference)
//
#include <hip/hip_runtime.h>
#include <stdint.h>
#include <stddef.h>

#define SEQ 4096
#define DIM 1024

typedef __bf16 bf16x8 __attribute__((ext_vector_type(8)));
typedef float floatx4 __attribute__((ext_vector_type(4)));
typedef unsigned short u16x8 __attribute__((ext_vector_type(8)));

__device__ __forceinline__ unsigned short f2b(float f) {
  union { float f; unsigned u; } v; v.f = f;
  unsigned u = v.u;
  unsigned r = (u + 0x7FFFu + ((u >> 16) & 1u)) >> 16;
  return (unsigned short)r;
}
__device__ __forceinline__ float b2f(unsigned short h) {
  union { unsigned u; float f; } v; v.u = ((unsigned)h) << 16;
  return v.f;
}

// ---------------- fused fp32 -> bf16 convert (x, wq, wk, wv in one launch) --------
__global__ __launch_bounds__(256)
void cvt_all(const float* __restrict__ x, const float* __restrict__ wq,
             const float* __restrict__ wk, const float* __restrict__ wv,
             unsigned short* __restrict__ xb, unsigned short* __restrict__ wqb,
             unsigned short* __restrict__ wkb, unsigned short* __restrict__ wvb) {
  const int bid = blockIdx.x;
  const float* src;
  unsigned short* dst;
  int off;
  if (bid < 4096)      { src = x;  dst = xb;  off = bid; }
  else if (bid < 5120) { src = wq; dst = wqb; off = bid - 4096; }
  else if (bid < 6144) { src = wk; dst = wkb; off = bid - 5120; }
  else                 { src = wv; dst = wvb; off = bid - 6144; }
  const int i = off * 1024 + threadIdx.x * 4;
  float4 f = *(const float4*)(src + i);
  ushort4 o;
  o.x = f2b(f.x); o.y = f2b(f.y); o.z = f2b(f.z); o.w = f2b(f.w);
  *(ushort4*)(dst + i) = o;
}

// ---------------- supertile swizzle: 8 consecutive pids share one B-tile ----------
__device__ __forceinline__ void swizzle_tiles(int gx, int gy, int& bx, int& by) {
  const int pid = blockIdx.y * gx + blockIdx.x;
  const int GM = 8;
  const int group = pid / (GM * gx);
  const int first = group * GM;
  const int gsz = (gy - first) < GM ? (gy - first) : GM;
  by = first + (pid % gsz);
  bx = (pid % (GM * gx)) / gsz;
}

// ---------------- legacy 128x128 core (kept for qkv_gemm) ----------------
__device__ __forceinline__ void gemm_core128(
    const unsigned short* __restrict__ A,
    const unsigned short* __restrict__ B,
    int lda, int ldb, int kext,
    unsigned short* As, unsigned short* Bs,
    floatx4 acc[4][4]) {
  const int tid  = threadIdx.x;
  const int lane = tid & 63;
  const int wave = tid >> 6;
  const int sub_m = (wave >> 1) * 64;
  const int sub_n = (wave & 1) * 64;
  const int col  = lane & 15;
  const int quad = lane >> 4;

  const int srow  = tid >> 3;
  const int sgran = (tid & 7) ^ (srow & 7);
  const int scol  = sgran * 8;
  const int dflat = tid * 8;

  const unsigned short* Ag = A + (size_t)srow * lda + scol;
  const unsigned short* Bg = B + (size_t)srow * ldb + scol;

  for (int k0 = 0; k0 < kext; k0 += 64) {
    __syncthreads();
#pragma unroll
    for (int j = 0; j < 4; j++) {
      __builtin_amdgcn_global_load_lds(
          (const __attribute__((address_space(1))) void*)(Ag + (size_t)(j * 32) * lda + k0),
          (__attribute__((address_space(3))) void*)(&As[j * 2048 + dflat]), 16, 0, 0);
      __builtin_amdgcn_global_load_lds(
          (const __attribute__((address_space(1))) void*)(Bg + (size_t)(j * 32) * ldb + k0),
          (__attribute__((address_space(3))) void*)(&Bs[j * 2048 + dflat]), 16, 0, 0);
    }
    __syncthreads();
#pragma unroll
    for (int ks = 0; ks < 64; ks += 32) {
      const int gbase = ks >> 3;
      bf16x8 af[4], bfr[4];
#pragma unroll
      for (int i = 0; i < 4; i++) {
        const int R = sub_m + 16 * i + col;
        const int slot = (gbase + quad) ^ (R & 7);
        af[i] = *(const bf16x8*)&As[R * 64 + slot * 8];
      }
#pragma unroll
      for (int j = 0; j < 4; j++) {
        const int R = sub_n + 16 * j + col;
        const int slot = (gbase + quad) ^ (R & 7);
        bfr[j] = *(const bf16x8*)&Bs[R * 64 + slot * 8];
      }
#pragma unroll
      for (int i = 0; i < 4; i++)
#pragma unroll
        for (int j = 0; j < 4; j++)
          acc[i][j] = __builtin_amdgcn_mfma_f32_16x16x32_bf16(af[i], bfr[j],
                                                              acc[i][j], 0, 0, 0);
    }
  }
}

// ---------------- fused QKV: z=0 Q, z=1 K, z=2 V^T (unchanged) ----------
__global__ __launch_bounds__(256, 2)
void qkv_gemm(const unsigned short* __restrict__ xb,
              const unsigned short* __restrict__ wqb,
              const unsigned short* __restrict__ wkb,
              const unsigned short* __restrict__ wvb,
              const float* __restrict__ bq, const float* __restrict__ bk,
              const float* __restrict__ bv,
              unsigned short* __restrict__ qb, unsigned short* __restrict__ kb,
              unsigned short* __restrict__ vtb) {
  __shared__ unsigned short As[8192];
  __shared__ unsigned short Bs[8192];
  const int z = blockIdx.z;
  const int pid = blockIdx.x;   // 0..255

  floatx4 acc[4][4];
#pragma unroll
  for (int i = 0; i < 4; i++)
#pragma unroll
    for (int j = 0; j < 4; j++) acc[i][j] = (floatx4)0.0f;

  const int lane = threadIdx.x & 63;
  const int wave = threadIdx.x >> 6;
  const int sub_m = (wave >> 1) * 64;
  const int sub_n = (wave & 1) * 64;
  const int col  = lane & 15;
  const int quad = lane >> 4;

  if (z < 2) {
    const unsigned short* W = z ? wkb : wqb;
    const float* bias = z ? bk : bq;
    unsigned short* outp = z ? kb : qb;
    const int by = pid >> 3, bx = pid & 7;
    const int tile_m = by * 128, tile_n = bx * 128;

    gemm_core128(xb + (size_t)tile_m * DIM, W + (size_t)tile_n * DIM,
                 DIM, DIM, DIM, As, Bs, acc);

    float biasv[4];
#pragma unroll
    for (int j = 0; j < 4; j++) biasv[j] = bias[tile_n + sub_n + 16 * j + col];
#pragma unroll
    for (int i = 0; i < 4; i++)
#pragma unroll
      for (int j = 0; j < 4; j++)
#pragma unroll
        for (int r = 0; r < 4; r++) {
          const int m = tile_m + sub_m + 16 * i + quad * 4 + r;
          const int n = tile_n + sub_n + 16 * j + col;
          outp[(size_t)m * DIM + n] = f2b(acc[i][j][r] + biasv[j]);
        }
  } else {
    const int by = pid >> 5, bx = pid & 31;
    const int tile_m = by * 128, tile_n = bx * 128;

    gemm_core128(wvb + (size_t)tile_m * DIM, xb + (size_t)tile_n * DIM,
                 DIM, DIM, DIM, As, Bs, acc);

#pragma unroll
    for (int i = 0; i < 4; i++) {
      const float* bp = &bv[tile_m + sub_m + 16 * i + quad * 4];
      float bm[4];
#pragma unroll
      for (int r = 0; r < 4; r++) bm[r] = bp[r];
#pragma unroll
      for (int j = 0; j < 4; j++)
#pragma unroll
        for (int r = 0; r < 4; r++) {
          const int m = tile_m + sub_m + 16 * i + quad * 4 + r;
          const int n = tile_n + sub_n + 16 * j + col;
          vtb[(size_t)m * SEQ + n] = f2b(acc[i][j][r] + bm[r]);
        }
    }
  }
}

// ================= 256x256 8-phase core — clobber-free waitcnts ===========
// Identical ledger to round 3. Waitcnt asms have NO memory clobber (m201
// conformance): stages (side-effecting intrinsics) keep program order vs the
// volatile asms, so the vmcnt arithmetic holds, but ds_reads are free to float
// into MFMA clusters across phases. Hazard pins: sched_barrier(0) after each
// lgkmcnt(0) (rule #18: MFMA must not hoist above its operand reads) and after
// each vmcnt wait (next-tile ds_reads must not hoist above buffer certification).
__device__ __forceinline__ void gemm_core256x256(
    const unsigned short* __restrict__ A,
    const unsigned short* __restrict__ B,
    int lda, int ldb, int nt,
    unsigned short* As, unsigned short* Bs,
    floatx4 (&acc)[8][4]) {
  const int tid  = threadIdx.x;
  const int lane = tid & 63;
  const int wid  = tid >> 6;
  const int wm   = wid >> 2;
  const int wn   = wid & 3;
  const int col  = lane & 15;
  const int quad = lane >> 4;
  const int c7   = col & 7;

  const int srow  = tid >> 3;
  const int sgran = (tid & 7) ^ (srow & 7);
  const int dflat = tid * 8;
  const unsigned short* Ag = A + (size_t)srow * lda + sgran * 8;
  const unsigned short* Bg = B + (size_t)srow * ldb + sgran * 8;

  auto stage_a = [&](int bsel, int kt, int h) {
#pragma unroll
    for (int j = 0; j < 2; j++)
      __builtin_amdgcn_global_load_lds(
          (const __attribute__((address_space(1))) void*)(
              Ag + (size_t)(h * 128 + j * 64) * lda + (size_t)kt * 64),
          (__attribute__((address_space(3))) void*)(
              &As[bsel * 16384 + h * 8192 + j * 4096 + dflat]),
          16, 0, 0);
  };
  auto stage_b = [&](int bsel, int kt, int h) {
#pragma unroll
    for (int j = 0; j < 2; j++)
      __builtin_amdgcn_global_load_lds(
          (const __attribute__((address_space(1))) void*)(
              Bg + (size_t)(h * 128 + j * 64) * ldb + (size_t)kt * 64),
          (__attribute__((address_space(3))) void*)(
              &Bs[bsel * 16384 + h * 8192 + j * 4096 + dflat]),
          16, 0, 0);
  };

  const int slot0 = (quad ^ c7) * 8;
  const int slot1 = ((4 + quad) ^ c7) * 8;
  const unsigned short* Ard = As + (size_t)(wm * 64 + col) * 64;
  const unsigned short* Brd = Bs + (size_t)(wn * 64 + col) * 64;

  // prologue: tile0 fully + tile1 {B0,B1,A0}
  stage_a(0, 0, 0); stage_a(0, 0, 1);
  stage_b(0, 0, 0); stage_b(0, 0, 1);
  stage_b(1, 1, 0); stage_b(1, 1, 1); stage_a(1, 1, 0);
  asm volatile("s_waitcnt vmcnt(6)");
  __builtin_amdgcn_sched_barrier(0);
  __builtin_amdgcn_s_barrier();

  for (int t = 0; t < nt; ++t) {
    const int buf  = t & 1;
    const int abuf = buf * 16384;
    const int bbuf = buf * 16384;
    bf16x8 bfr[4][2];
#pragma unroll
    for (int s = 0; s < 4; ++s) {
      if (s == 0) {
#pragma unroll
        for (int j = 0; j < 4; j++) {
          bfr[j][0] = *(const bf16x8*)&Brd[bbuf + j * 1024 + slot0];
          bfr[j][1] = *(const bf16x8*)&Brd[bbuf + j * 1024 + slot1];
        }
      }
      bf16x8 af[2][2];
      const int rb = abuf + ((s & 2) ? 8192 : 0) + (s & 1) * 2048;
#pragma unroll
      for (int k = 0; k < 2; k++) {
        af[k][0] = *(const bf16x8*)&Ard[rb + k * 1024 + slot0];
        af[k][1] = *(const bf16x8*)&Ard[rb + k * 1024 + slot1];
      }
      if (s == 0)      { if (t + 1 < nt) stage_a(buf ^ 1, t + 1, 1); }
      else if (s == 1) { if (t + 2 < nt) stage_b(buf, t + 2, 0); }
      else if (s == 2) { if (t + 2 < nt) stage_b(buf, t + 2, 1); }
      else {
        if (t + 2 < nt) {
          stage_a(buf, t + 2, 0);
          asm volatile("s_waitcnt vmcnt(6)");
          __builtin_amdgcn_sched_barrier(0);
        } else if (t + 1 < nt) {
          asm volatile("s_waitcnt vmcnt(0)");
          __builtin_amdgcn_sched_barrier(0);
        }
      }
      __builtin_amdgcn_s_barrier();
      asm volatile("s_waitcnt lgkmcnt(0)");
      __builtin_amdgcn_sched_barrier(0);
      __builtin_amdgcn_s_setprio(1);
#pragma unroll
      for (int k = 0; k < 2; k++)
#pragma unroll
        for (int j = 0; j < 4; j++)
#pragma unroll
          for (int ks = 0; ks < 2; ks++)
            acc[2 * s + k][j] = __builtin_amdgcn_mfma_f32_16x16x32_bf16(
                af[k][ks], bfr[j][ks], acc[2 * s + k][j], 0, 0, 0);
      __builtin_amdgcn_s_setprio(0);
      __builtin_amdgcn_s_barrier();
    }
  }
}

// ================= 256x128 2-phase triple-buffered core — clobber-free ==========
// Identical ledger to round 3; waitcnt asms clobber-free, hazard pins as above.
__device__ __forceinline__ void gemm_core256x128(
    const unsigned short* __restrict__ A,
    const unsigned short* __restrict__ B,
    int lda, int ldb, int nt,
    unsigned short* As, unsigned short* Bs,
    floatx4 (&acc)[8][2]) {
  const int tid  = threadIdx.x;
  const int lane = tid & 63;
  const int wid  = tid >> 6;
  const int wm   = wid >> 2;
  const int wn   = wid & 3;
  const int col  = lane & 15;
  const int quad = lane >> 4;
  const int c7   = col & 7;

  const int srow  = tid >> 3;
  const int sgran = (tid & 7) ^ (srow & 7);
  const int dflat = tid * 8;
  const unsigned short* Ag = A + (size_t)srow * lda + sgran * 8;
  const unsigned short* Bg = B + (size_t)srow * ldb + sgran * 8;

  auto stage_a = [&](int bsel, int kt, int h) {
#pragma unroll
    for (int j = 0; j < 2; j++)
      __builtin_amdgcn_global_load_lds(
          (const __attribute__((address_space(1))) void*)(
              Ag + (size_t)(h * 128 + j * 64) * lda + (size_t)kt * 64),
          (__attribute__((address_space(3))) void*)(
              &As[bsel * 16384 + h * 8192 + j * 4096 + dflat]),
          16, 0, 0);
  };
  auto stage_b = [&](int bsel, int kt) {
#pragma unroll
    for (int j = 0; j < 2; j++)
      __builtin_amdgcn_global_load_lds(
          (const __attribute__((address_space(1))) void*)(
              Bg + (size_t)(j * 64) * ldb + (size_t)kt * 64),
          (__attribute__((address_space(3))) void*)(
              &Bs[bsel * 8192 + j * 4096 + dflat]),
          16, 0, 0);
  };

  const int slot0 = (quad ^ c7) * 8;
  const int slot1 = ((4 + quad) ^ c7) * 8;
  const unsigned short* Ard = As + (size_t)(wm * 64 + col) * 64;
  const unsigned short* Brd = Bs + (size_t)(wn * 32 + col) * 64;

  // prologue: tiles 0 and 1 fully staged into bufs 0,1
  stage_a(0, 0, 0); stage_a(0, 0, 1); stage_b(0, 0);
  stage_a(1, 1, 0); stage_a(1, 1, 1); stage_b(1, 1);
  asm volatile("s_waitcnt vmcnt(6)");  // tile0's 6 landed
  __builtin_amdgcn_sched_barrier(0);
  __builtin_amdgcn_s_barrier();

  int cur = 0, stg = 2;
  for (int t = 0; t < nt; ++t) {
    const int abuf = cur * 16384;
    const int bbuf = cur * 8192;
    // ---- phase 0: B all + A-half0, stage (t+2).A ----
    bf16x8 bfr[2][2];
#pragma unroll
    for (int j = 0; j < 2; j++) {
      bfr[j][0] = *(const bf16x8*)&Brd[bbuf + j * 1024 + slot0];
      bfr[j][1] = *(const bf16x8*)&Brd[bbuf + j * 1024 + slot1];
    }
    {
      bf16x8 af[4][2];
#pragma unroll
      for (int i = 0; i < 4; i++) {
        af[i][0] = *(const bf16x8*)&Ard[abuf + i * 1024 + slot0];
        af[i][1] = *(const bf16x8*)&Ard[abuf + i * 1024 + slot1];
      }
      if (t + 2 < nt) { stage_a(stg, t + 2, 0); stage_a(stg, t + 2, 1); }
      __builtin_amdgcn_s_barrier();
      asm volatile("s_waitcnt lgkmcnt(0)");
      __builtin_amdgcn_sched_barrier(0);
      __builtin_amdgcn_s_setprio(1);
#pragma unroll
      for (int i = 0; i < 4; i++)
#pragma unroll
        for (int j = 0; j < 2; j++)
#pragma unroll
          for (int ks = 0; ks < 2; ks++)
            acc[i][j] = __builtin_amdgcn_mfma_f32_16x16x32_bf16(
                af[i][ks], bfr[j][ks], acc[i][j], 0, 0, 0);
      __builtin_amdgcn_s_setprio(0);
      __builtin_amdgcn_s_barrier();
    }
    // ---- phase 1: A-half1, stage (t+2).B + counted wait ----
    {
      bf16x8 af[4][2];
#pragma unroll
      for (int i = 0; i < 4; i++) {
        af[i][0] = *(const bf16x8*)&Ard[abuf + 8192 + i * 1024 + slot0];
        af[i][1] = *(const bf16x8*)&Ard[abuf + 8192 + i * 1024 + slot1];
      }
      if (t + 2 < nt) {
        stage_b(stg, t + 2);
        asm volatile("s_waitcnt vmcnt(6)");  // all of t+1 landed
        __builtin_amdgcn_sched_barrier(0);
      } else if (t + 1 < nt) {
        asm volatile("s_waitcnt vmcnt(0)");  // tail drain, once
        __builtin_amdgcn_sched_barrier(0);
      }
      __builtin_amdgcn_s_barrier();
      asm volatile("s_waitcnt lgkmcnt(0)");
      __builtin_amdgcn_sched_barrier(0);
      __builtin_amdgcn_s_setprio(1);
#pragma unroll
      for (int i = 0; i < 4; i++)
#pragma unroll
        for (int j = 0; j < 2; j++)
#pragma unroll
          for (int ks = 0; ks < 2; ks++)
            acc[4 + i][j] = __builtin_amdgcn_mfma_f32_16x16x32_bf16(
                af[i][ks], bfr[j][ks], acc[4 + i][j], 0, 0, 0);
      __builtin_amdgcn_s_setprio(0);
      __builtin_amdgcn_s_barrier();
    }
    cur = (cur == 2) ? 0 : cur + 1;
    stg = (stg == 2) ? 0 : stg + 1;
  }
}

// ---------------- scores = (Q K^T) * scale, 256x256 8-phase, XCD-banded ----------
__global__ __launch_bounds__(512, 2)
void score_gemm(const unsigned short* __restrict__ qb,
                const unsigned short* __restrict__ kb,
                unsigned short* __restrict__ sc, float scale) {
  __shared__ unsigned short As[32768];
  __shared__ unsigned short Bs[32768];
  const int pid = blockIdx.x;            // 0..255, 1 block/CU
  const int xcd = pid & 7;
  const int local = pid >> 3;            // 0..31
  const int bx = xcd * 2 + (local & 1);  // 2 N-tiles pinned per XCD (1 MiB K in L2)
  const int by = local >> 1;             // 0..15
  const int tile_m = by * 256, tile_n = bx * 256;

  floatx4 acc[8][4];
#pragma unroll
  for (int i = 0; i < 8; i++)
#pragma unroll
    for (int j = 0; j < 4; j++) acc[i][j] = (floatx4)0.0f;

  gemm_core256x256(qb + (size_t)tile_m * DIM, kb + (size_t)tile_n * DIM,
                   DIM, DIM, DIM / 64, As, Bs, acc);

  const int lane = threadIdx.x & 63;
  const int wid  = threadIdx.x >> 6;
  const int wm = wid >> 2, wn = wid & 3;
  const int col = lane & 15, quad = lane >> 4;
#pragma unroll
  for (int i = 0; i < 8; i++) {
    const int m0 = tile_m + ((i & 4) ? 128 : 0) + wm * 64 + (i & 3) * 16 + quad * 4;
#pragma unroll
    for (int j = 0; j < 4; j++) {
      const int n = tile_n + wn * 64 + j * 16 + col;
#pragma unroll
      for (int r = 0; r < 4; r++)
        sc[(size_t)(m0 + r) * SEQ + n] = f2b(acc[i][j][r] * scale);
    }
  }
}

// ---------------- PV: 256x128 2-phase, split-K=2 (z=0 -> d_out, z=1 -> part) -----
__global__ __launch_bounds__(512, 2)
void pv_gemm(const unsigned short* __restrict__ sc,
             const unsigned short* __restrict__ vtb,
             float* __restrict__ out0, float* __restrict__ out1) {
  __shared__ unsigned short As[49152];   // 3 x 32 KiB
  __shared__ unsigned short Bs[24576];   // 3 x 16 KiB
  const int z = blockIdx.z;
  const int koff = z * (SEQ / 2);
  float* C = z ? out1 : out0;
  int bx, by;
  swizzle_tiles(gridDim.x, gridDim.y, bx, by);
  const int tile_m = by * 256;
  const int tile_n = bx * 128;

  floatx4 acc[8][2];
#pragma unroll
  for (int i = 0; i < 8; i++)
#pragma unroll
    for (int j = 0; j < 2; j++) acc[i][j] = (floatx4)0.0f;

  gemm_core256x128(sc + (size_t)tile_m * SEQ + koff,
                   vtb + (size_t)tile_n * SEQ + koff,
                   SEQ, SEQ, (SEQ / 2) / 64, As, Bs, acc);

  const int lane = threadIdx.x & 63;
  const int wid  = threadIdx.x >> 6;
  const int wm = wid >> 2, wn = wid & 3;
  const int col = lane & 15, quad = lane >> 4;
#pragma unroll
  for (int i = 0; i < 8; i++) {
    const int m0 = tile_m + ((i & 4) ? 128 : 0) + wm * 64 + (i & 3) * 16 + quad * 4;
#pragma unroll
    for (int j = 0; j < 2; j++) {
      const int n = tile_n + wn * 32 + j * 16 + col;
#pragma unroll
      for (int r = 0; r < 4; r++)
        C[(size_t)(m0 + r) * DIM + n] = acc[i][j][r];
    }
  }
}

// ---------------- out += partial ----------------
__global__ __launch_bounds__(256)
void reduce_add(float* __restrict__ out, const float* __restrict__ part) {
  const int i = (blockIdx.x * 256 + threadIdx.x) * 4;
  float4 a = *(const float4*)(out + i);
  float4 b = *(const float4*)(part + i);
  a.x += b.x; a.y += b.y; a.z += b.z; a.w += b.w;
  *(float4*)(out + i) = a;
}

// ---------------- in-place row softmax on bf16 [SEQ, SEQ] ----------------
__global__ __launch_bounds__(256)
void softmax_inplace(unsigned short* __restrict__ P) {
  const int row = blockIdx.x;
  unsigned short* p = P + (size_t)row * SEQ;
  const int tid  = threadIdx.x;
  const int lane = tid & 63;
  const int wave = tid >> 6;

  u16x8 raw0 = *(const u16x8*)(p + tid * 16);
  u16x8 raw1 = *(const u16x8*)(p + tid * 16 + 8);
  float v[16];
#pragma unroll
  for (int k = 0; k < 8; k++) v[k] = b2f(raw0[k]);
#pragma unroll
  for (int k = 0; k < 8; k++) v[8 + k] = b2f(raw1[k]);

  float mx = -1e30f;
#pragma unroll
  for (int k = 0; k < 16; k++) mx = fmaxf(mx, v[k]);
#pragma unroll
  for (int off = 32; off > 0; off >>= 1) mx = fmaxf(mx, __shfl_xor(mx, off, 64));
  __shared__ float redm[4];
  __shared__ float reds[4];
  if (lane == 0) redm[wave] = mx;
  __syncthreads();
  mx = fmaxf(fmaxf(redm[0], redm[1]), fmaxf(redm[2], redm[3]));

  float sum = 0.0f;
#pragma unroll
  for (int k = 0; k < 16; k++) {
    v[k] = exp2f((v[k] - mx) * 1.44269504f);
    sum += v[k];
  }
#pragma unroll
  for (int off = 32; off > 0; off >>= 1) sum += __shfl_xor(sum, off, 64);
  if (lane == 0) reds[wave] = sum;
  __syncthreads();
  sum = reds[0] + reds[1] + reds[2] + reds[3];
  const float inv = 1.0f / sum;

  u16x8 o0, o1;
#pragma unroll
  for (int k = 0; k < 8; k++) o0[k] = f2b(v[k] * inv);
#pragma unroll
  for (int k = 0; k < 8; k++) o1[k] = f2b(v[8 + k] * inv);
  *(u16x8*)(p + tid * 16) = o0;
  *(u16x8*)(p + tid * 16 + 8) = o1;
}

extern "C" void kernel_launch(void* const* d_in, const int* in_sizes, int n_in,
                              void* d_out, int out_size, void* d_ws, size_t ws_size,
                              hipStream_t stream) {
  const float* x  = (const float*)d_in[0];
  const float* wq = (const float*)d_in[1];
  const float* bq = (const float*)d_in[2];
  const float* wk = (const float*)d_in[3];
  const float* bk = (const float*)d_in[4];
  const float* wv = (const float*)d_in[5];
  const float* bv = (const float*)d_in[6];

  uint8_t* ws = (uint8_t*)d_ws;
  unsigned short* xb  = (unsigned short*)(ws);                      // [0,8)   MiB
  unsigned short* wqb = (unsigned short*)(ws + ((size_t)8  << 20)); // [8,10)
  unsigned short* wkb = (unsigned short*)(ws + ((size_t)10 << 20)); // [10,12)
  unsigned short* wvb = (unsigned short*)(ws + ((size_t)12 << 20)); // [12,14)
  unsigned short* qb  = (unsigned short*)(ws + ((size_t)14 << 20)); // [14,22)
  unsigned short* kb  = (unsigned short*)(ws + ((size_t)22 << 20)); // [22,30)
  unsigned short* vtb = (unsigned short*)(ws + ((size_t)30 << 20)); // [30,38)  V^T [DIM][SEQ]
  unsigned short* sc  = (unsigned short*)(ws + ((size_t)38 << 20)); // [38,70)  scores/attn
  float*          part = (float*)(ws);                              // [0,16)   PV partial

  // fp32 -> bf16
  cvt_all<<<7168, 256, 0, stream>>>(x, wq, wk, wv, xb, wqb, wkb, wvb);

  // fused Q / K / V^T projections (768 blocks, legacy 128 core)
  qkv_gemm<<<dim3(256, 1, 3), 256, 0, stream>>>(
      xb, wqb, wkb, wvb, bq, bk, bv, qb, kb, vtb);

  // scores = (Q K^T) / sqrt(D)   (256 blocks x 512 thr, 256^2 8-phase)
  score_gemm<<<dim3(256), 512, 0, stream>>>(qb, kb, sc, 0.03125f);

  // softmax rows in place
  softmax_inplace<<<SEQ, 256, 0, stream>>>(sc);

  // out = attn @ V, split-K=2 (256 blocks x 512 thr, 256x128 2-phase)
  pv_gemm<<<dim3(8, 16, 2), 512, 0, stream>>>(
      sc, vtb, (float*)d_out, part);

  // d_out += part
  reduce_add<<<(SEQ * DIM) / 1024, 256, 0, stream>>>((float*)d_out, part);
}

// Round 5
// 217.383 us; speedup vs baseline: 1.0111x; 1.0111x over previous
//
#include <hip/hip_runtime.h>
#include <stdint.h>
#include <stddef.h>

#define SEQ 4096
#define DIM 1024

typedef __bf16 bf16x8 __attribute__((ext_vector_type(8)));
typedef float floatx4 __attribute__((ext_vector_type(4)));
typedef unsigned short u16x8 __attribute__((ext_vector_type(8)));

__device__ __forceinline__ unsigned short f2b(float f) {
  union { float f; unsigned u; } v; v.f = f;
  unsigned u = v.u;
  unsigned r = (u + 0x7FFFu + ((u >> 16) & 1u)) >> 16;
  return (unsigned short)r;
}
__device__ __forceinline__ float b2f(unsigned short h) {
  union { unsigned u; float f; } v; v.u = ((unsigned)h) << 16;
  return v.f;
}

// ---------------- fused fp32 -> bf16 convert (x, wq, wk, wv in one launch) --------
__global__ __launch_bounds__(256)
void cvt_all(const float* __restrict__ x, const float* __restrict__ wq,
             const float* __restrict__ wk, const float* __restrict__ wv,
             unsigned short* __restrict__ xb, unsigned short* __restrict__ wqb,
             unsigned short* __restrict__ wkb, unsigned short* __restrict__ wvb) {
  const int bid = blockIdx.x;
  const float* src;
  unsigned short* dst;
  int off;
  if (bid < 4096)      { src = x;  dst = xb;  off = bid; }
  else if (bid < 5120) { src = wq; dst = wqb; off = bid - 4096; }
  else if (bid < 6144) { src = wk; dst = wkb; off = bid - 5120; }
  else                 { src = wv; dst = wvb; off = bid - 6144; }
  const int i = off * 1024 + threadIdx.x * 4;
  float4 f = *(const float4*)(src + i);
  ushort4 o;
  o.x = f2b(f.x); o.y = f2b(f.y); o.z = f2b(f.z); o.w = f2b(f.w);
  *(ushort4*)(dst + i) = o;
}

// ---------------- zero-fill d_out (enables atomic split-K accumulation) ----------
__global__ __launch_bounds__(256)
void zero_out(float* __restrict__ out) {
  const int i = (blockIdx.x * 256 + threadIdx.x) * 4;
  *(float4*)(out + i) = make_float4(0.f, 0.f, 0.f, 0.f);
}

// ---------------- supertile swizzle: 8 consecutive pids share one B-tile ----------
// Empirically (r1 vs r3 vs r4): this B-sharing M-walk cuts pv FETCH 135->49 MB;
// natural x-fastest order (A-sharing) does NOT (135 MB both times it was tried).
__device__ __forceinline__ void swizzle_tiles(int gx, int gy, int& bx, int& by) {
  const int pid = blockIdx.y * gx + blockIdx.x;
  const int GM = 8;
  const int group = pid / (GM * gx);
  const int first = group * GM;
  const int gsz = (gy - first) < GM ? (gy - first) : GM;
  by = first + (pid % gsz);
  bx = (pid % (GM * gx)) / gsz;
}

// ---------------- core 128x128 B^T-form bf16 GEMM (16x16x32 MFMA) ----------------
// C_tile[128,128] += A[0:128, :kext] * B[0:128, :kext]^T  (A,B pre-offset)
// LDS XOR-swizzle: granule g of row r at slot g^(r&7), source-column swizzled
// (global_load_lds dest is lane-ordered). Quad-rotated fragment reads measured
// conflict-free (r2/r4: SQ_LDS_BANK_CONFLICT = 0).
__device__ __forceinline__ void gemm_core128(
    const unsigned short* __restrict__ A,
    const unsigned short* __restrict__ B,
    int lda, int ldb, int kext,
    unsigned short* As, unsigned short* Bs,
    floatx4 acc[4][4]) {
  const int tid  = threadIdx.x;
  const int lane = tid & 63;
  const int wave = tid >> 6;
  const int sub_m = (wave >> 1) * 64;
  const int sub_n = (wave & 1) * 64;
  const int col  = lane & 15;
  const int quad = lane >> 4;

  const int srow  = tid >> 3;
  const int sgran = (tid & 7) ^ (srow & 7);
  const int scol  = sgran * 8;
  const int dflat = tid * 8;

  const unsigned short* Ag = A + (size_t)srow * lda + scol;
  const unsigned short* Bg = B + (size_t)srow * ldb + scol;

  for (int k0 = 0; k0 < kext; k0 += 64) {
    __syncthreads();
#pragma unroll
    for (int j = 0; j < 4; j++) {
      __builtin_amdgcn_global_load_lds(
          (const __attribute__((address_space(1))) void*)(Ag + (size_t)(j * 32) * lda + k0),
          (__attribute__((address_space(3))) void*)(&As[j * 2048 + dflat]), 16, 0, 0);
      __builtin_amdgcn_global_load_lds(
          (const __attribute__((address_space(1))) void*)(Bg + (size_t)(j * 32) * ldb + k0),
          (__attribute__((address_space(3))) void*)(&Bs[j * 2048 + dflat]), 16, 0, 0);
    }
    __syncthreads();
#pragma unroll
    for (int ks = 0; ks < 64; ks += 32) {
      const int gbase = ks >> 3;
      bf16x8 af[4], bfr[4];
#pragma unroll
      for (int i = 0; i < 4; i++) {
        const int R = sub_m + 16 * i + col;
        const int slot = (gbase + quad) ^ (R & 7);
        af[i] = *(const bf16x8*)&As[R * 64 + slot * 8];
      }
#pragma unroll
      for (int j = 0; j < 4; j++) {
        const int R = sub_n + 16 * j + col;
        const int slot = (gbase + quad) ^ (R & 7);
        bfr[j] = *(const bf16x8*)&Bs[R * 64 + slot * 8];
      }
#pragma unroll
      for (int i = 0; i < 4; i++)
#pragma unroll
        for (int j = 0; j < 4; j++)
          acc[i][j] = __builtin_amdgcn_mfma_f32_16x16x32_bf16(af[i], bfr[j],
                                                              acc[i][j], 0, 0, 0);
    }
  }
}

// C/D layout (16x16): col = lane&15, row = quad*4 + reg   [verified m89/m91]

// ---------------- fused QKV: z=0 Q, z=1 K, z=2 V^T (= Wv x^T, coalesced) ----------
__global__ __launch_bounds__(256, 2)
void qkv_gemm(const unsigned short* __restrict__ xb,
              const unsigned short* __restrict__ wqb,
              const unsigned short* __restrict__ wkb,
              const unsigned short* __restrict__ wvb,
              const float* __restrict__ bq, const float* __restrict__ bk,
              const float* __restrict__ bv,
              unsigned short* __restrict__ qb, unsigned short* __restrict__ kb,
              unsigned short* __restrict__ vtb) {
  __shared__ unsigned short As[8192];
  __shared__ unsigned short Bs[8192];
  const int z = blockIdx.z;
  const int pid = blockIdx.x;   // 0..255

  floatx4 acc[4][4];
#pragma unroll
  for (int i = 0; i < 4; i++)
#pragma unroll
    for (int j = 0; j < 4; j++) acc[i][j] = (floatx4)0.0f;

  const int lane = threadIdx.x & 63;
  const int wave = threadIdx.x >> 6;
  const int sub_m = (wave >> 1) * 64;
  const int sub_n = (wave & 1) * 64;
  const int col  = lane & 15;
  const int quad = lane >> 4;

  if (z < 2) {
    // Q or K: [SEQ, DIM] = x[SEQ,K] * W[DIM,K]^T + b[n]
    const unsigned short* W = z ? wkb : wqb;
    const float* bias = z ? bk : bq;
    unsigned short* outp = z ? kb : qb;
    const int by = pid >> 3, bx = pid & 7;
    const int tile_m = by * 128, tile_n = bx * 128;

    gemm_core128(xb + (size_t)tile_m * DIM, W + (size_t)tile_n * DIM,
                 DIM, DIM, DIM, As, Bs, acc);

    float biasv[4];
#pragma unroll
    for (int j = 0; j < 4; j++) biasv[j] = bias[tile_n + sub_n + 16 * j + col];
#pragma unroll
    for (int i = 0; i < 4; i++)
#pragma unroll
      for (int j = 0; j < 4; j++)
#pragma unroll
        for (int r = 0; r < 4; r++) {
          const int m = tile_m + sub_m + 16 * i + quad * 4 + r;
          const int n = tile_n + sub_n + 16 * j + col;
          outp[(size_t)m * DIM + n] = f2b(acc[i][j][r] + biasv[j]);
        }
  } else {
    // V^T[DIM, SEQ] = Wv[DIM,K] * x[SEQ,K]^T + bv[m]  (row-major coalesced stores)
    const int by = pid >> 5, bx = pid & 31;
    const int tile_m = by * 128, tile_n = bx * 128;

    gemm_core128(wvb + (size_t)tile_m * DIM, xb + (size_t)tile_n * DIM,
                 DIM, DIM, DIM, As, Bs, acc);

#pragma unroll
    for (int i = 0; i < 4; i++) {
      const float* bp = &bv[tile_m + sub_m + 16 * i + quad * 4];
      float bm[4];
#pragma unroll
      for (int r = 0; r < 4; r++) bm[r] = bp[r];
#pragma unroll
      for (int j = 0; j < 4; j++)
#pragma unroll
        for (int r = 0; r < 4; r++) {
          const int m = tile_m + sub_m + 16 * i + quad * 4 + r;
          const int n = tile_n + sub_n + 16 * j + col;
          vtb[(size_t)m * SEQ + n] = f2b(acc[i][j][r] + bm[r]);
        }
    }
  }
}

// ---------------- scores = (Q K^T) * scale, bf16 out ----------------
// XCD-banded tile map: assuming round-robin pid->XCD, each XCD owns a 4-wide
// N-band (its 1 MB of K-tiles stays hot in its private 4 MiB L2) and walks M;
// Q streams in the same order on all XCDs -> served by shared L3.
__global__ __launch_bounds__(256, 2)
void score_gemm(const unsigned short* __restrict__ qb,
                const unsigned short* __restrict__ kb,
                unsigned short* __restrict__ sc, float scale) {
  __shared__ unsigned short As[8192];
  __shared__ unsigned short Bs[8192];
  const int pid = blockIdx.y * gridDim.x + blockIdx.x;
  const int xcd = pid & 7;
  const int local = pid >> 3;            // 0..127
  const int bx = xcd * 4 + (local & 3);  // N-tile pinned to XCD band
  const int by = local >> 2;             // 0..31
  const int tile_m = by * 128;
  const int tile_n = bx * 128;

  floatx4 acc[4][4];
#pragma unroll
  for (int i = 0; i < 4; i++)
#pragma unroll
    for (int j = 0; j < 4; j++) acc[i][j] = (floatx4)0.0f;

  gemm_core128(qb + (size_t)tile_m * DIM, kb + (size_t)tile_n * DIM,
               DIM, DIM, DIM, As, Bs, acc);

  const int lane = threadIdx.x & 63;
  const int wave = threadIdx.x >> 6;
  const int sub_m = (wave >> 1) * 64;
  const int sub_n = (wave & 1) * 64;
  const int col  = lane & 15;
  const int quad = lane >> 4;
#pragma unroll
  for (int i = 0; i < 4; i++)
#pragma unroll
    for (int j = 0; j < 4; j++)
#pragma unroll
      for (int r = 0; r < 4; r++) {
        const int m = tile_m + sub_m + 16 * i + quad * 4 + r;
        const int n = tile_n + sub_n + 16 * j + col;
        sc[(size_t)m * SEQ + n] = f2b(acc[i][j][r] * scale);
      }
}

// ---------------- PV split-K=2: both halves atomically accumulate into d_out -----
// d_out is pre-zeroed; each element receives exactly two f32 atomic adds (one per
// K-half). f32 add is commutative -> bit-identical to the former store+reduce_add
// (0+a+b == a+b in either arrival order). Removes part buffer + reduce kernel.
__global__ __launch_bounds__(256, 2)
void pv_gemm(const unsigned short* __restrict__ sc,
             const unsigned short* __restrict__ vtb,
             float* __restrict__ out) {
  __shared__ unsigned short As[8192];
  __shared__ unsigned short Bs[8192];
  const int z = blockIdx.z;
  const int koff = z * (SEQ / 2);
  int bx, by;
  swizzle_tiles(gridDim.x, gridDim.y, bx, by);
  const int tile_m = by * 128;
  const int tile_n = bx * 128;

  floatx4 acc[4][4];
#pragma unroll
  for (int i = 0; i < 4; i++)
#pragma unroll
    for (int j = 0; j < 4; j++) acc[i][j] = (floatx4)0.0f;

  gemm_core128(sc + (size_t)tile_m * SEQ + koff,
               vtb + (size_t)tile_n * SEQ + koff,
               SEQ, SEQ, SEQ / 2, As, Bs, acc);

  const int lane = threadIdx.x & 63;
  const int wave = threadIdx.x >> 6;
  const int sub_m = (wave >> 1) * 64;
  const int sub_n = (wave & 1) * 64;
  const int col  = lane & 15;
  const int quad = lane >> 4;
#pragma unroll
  for (int i = 0; i < 4; i++)
#pragma unroll
    for (int j = 0; j < 4; j++)
#pragma unroll
      for (int r = 0; r < 4; r++) {
        const int m = tile_m + sub_m + 16 * i + quad * 4 + r;
        const int n = tile_n + sub_n + 16 * j + col;
        atomicAdd(&out[(size_t)m * DIM + n], acc[i][j][r]);
      }
}

// ---------------- in-place row softmax on bf16 [SEQ, SEQ] ----------------
__global__ __launch_bounds__(256)
void softmax_inplace(unsigned short* __restrict__ P) {
  const int row = blockIdx.x;
  unsigned short* p = P + (size_t)row * SEQ;
  const int tid  = threadIdx.x;
  const int lane = tid & 63;
  const int wave = tid >> 6;

  u16x8 raw0 = *(const u16x8*)(p + tid * 16);
  u16x8 raw1 = *(const u16x8*)(p + tid * 16 + 8);
  float v[16];
#pragma unroll
  for (int k = 0; k < 8; k++) v[k] = b2f(raw0[k]);
#pragma unroll
  for (int k = 0; k < 8; k++) v[8 + k] = b2f(raw1[k]);

  float mx = -1e30f;
#pragma unroll
  for (int k = 0; k < 16; k++) mx = fmaxf(mx, v[k]);
#pragma unroll
  for (int off = 32; off > 0; off >>= 1) mx = fmaxf(mx, __shfl_xor(mx, off, 64));
  __shared__ float redm[4];
  __shared__ float reds[4];
  if (lane == 0) redm[wave] = mx;
  __syncthreads();
  mx = fmaxf(fmaxf(redm[0], redm[1]), fmaxf(redm[2], redm[3]));

  float sum = 0.0f;
#pragma unroll
  for (int k = 0; k < 16; k++) {
    v[k] = exp2f((v[k] - mx) * 1.44269504f);
    sum += v[k];
  }
#pragma unroll
  for (int off = 32; off > 0; off >>= 1) sum += __shfl_xor(sum, off, 64);
  if (lane == 0) reds[wave] = sum;
  __syncthreads();
  sum = reds[0] + reds[1] + reds[2] + reds[3];
  const float inv = 1.0f / sum;

  u16x8 o0, o1;
#pragma unroll
  for (int k = 0; k < 8; k++) o0[k] = f2b(v[k] * inv);
#pragma unroll
  for (int k = 0; k < 8; k++) o1[k] = f2b(v[8 + k] * inv);
  *(u16x8*)(p + tid * 16) = o0;
  *(u16x8*)(p + tid * 16 + 8) = o1;
}

extern "C" void kernel_launch(void* const* d_in, const int* in_sizes, int n_in,
                              void* d_out, int out_size, void* d_ws, size_t ws_size,
                              hipStream_t stream) {
  const float* x  = (const float*)d_in[0];
  const float* wq = (const float*)d_in[1];
  const float* bq = (const float*)d_in[2];
  const float* wk = (const float*)d_in[3];
  const float* bk = (const float*)d_in[4];
  const float* wv = (const float*)d_in[5];
  const float* bv = (const float*)d_in[6];

  uint8_t* ws = (uint8_t*)d_ws;
  unsigned short* xb  = (unsigned short*)(ws);                      // [0,8)   MiB
  unsigned short* wqb = (unsigned short*)(ws + ((size_t)8  << 20)); // [8,10)
  unsigned short* wkb = (unsigned short*)(ws + ((size_t)10 << 20)); // [10,12)
  unsigned short* wvb = (unsigned short*)(ws + ((size_t)12 << 20)); // [12,14)
  unsigned short* qb  = (unsigned short*)(ws + ((size_t)14 << 20)); // [14,22)
  unsigned short* kb  = (unsigned short*)(ws + ((size_t)22 << 20)); // [22,30)
  unsigned short* vtb = (unsigned short*)(ws + ((size_t)30 << 20)); // [30,38)  V^T [DIM][SEQ]
  unsigned short* sc  = (unsigned short*)(ws + ((size_t)38 << 20)); // [38,70)  scores/attn

  // fp32 -> bf16
  cvt_all<<<7168, 256, 0, stream>>>(x, wq, wk, wv, xb, wqb, wkb, wvb);

  // zero d_out for atomic split-K accumulation (no dependency on cvt)
  zero_out<<<(SEQ * DIM) / 1024, 256, 0, stream>>>((float*)d_out);

  // fused Q / K / V^T projections (768 blocks)
  qkv_gemm<<<dim3(256, 1, 3), 256, 0, stream>>>(
      xb, wqb, wkb, wvb, bq, bk, bv, qb, kb, vtb);

  // scores = (Q K^T) / sqrt(D)   (1024 blocks, XCD-banded)
  score_gemm<<<dim3(SEQ / 128, SEQ / 128), 256, 0, stream>>>(qb, kb, sc, 0.03125f);

  // softmax rows in place
  softmax_inplace<<<SEQ, 256, 0, stream>>>(sc);

  // out = attn @ V, split-K=2 (512 blocks): both halves atomicAdd into d_out
  pv_gemm<<<dim3(DIM / 128, SEQ / 128, 2), 256, 0, stream>>>(
      sc, vtb, (float*)d_out);
}